// Round 9
// baseline (466.900 us; speedup 1.0000x reference)
//
#include <hip/hip_runtime.h>

#define N_NODES   50000
#define N_EDGES   800000
#define NUM_GRAPHS 64
#define D         128
#define SLOPE     0.01

typedef double d4 __attribute__((ext_vector_type(4)));

__device__ __forceinline__ double dleaky(double v) { return v >= 0.0 ? v : SLOPE * v; }

// ---------------- zero ----------------
__global__ void zero_kernel(int* __restrict__ p, int n) {
    int i = blockIdx.x * blockDim.x + threadIdx.x;
    if (i < n) p[i] = 0;
}

// ---------------- degree histogram (by col) ----------------
__global__ void hist_kernel(const int* __restrict__ col, int* __restrict__ hist, int E) {
    int e = blockIdx.x * blockDim.x + threadIdx.x;
    if (e < E) atomicAdd(&hist[col[e]], 1);
}

// ---------------- dinv = 1/sqrt(deg+1) in double ----------------
__global__ void dinv_kernel(const int* __restrict__ hist, double* __restrict__ dinvd, int n) {
    int i = blockIdx.x * blockDim.x + threadIdx.x;
    if (i < n) dinvd[i] = 1.0 / sqrt((double)hist[i] + 1.0);
}

// ---------------- multi-block exclusive scan (3 kernels) ----------------
__global__ __launch_bounds__(256) void scan1(const int* __restrict__ hist,
                                             int* __restrict__ start,
                                             int* __restrict__ bsum, int n) {
    __shared__ int tmp[256];
    const int tid = threadIdx.x;
    int base = blockIdx.x * 1024 + tid * 4;
    int v[4]; int s = 0;
#pragma unroll
    for (int i = 0; i < 4; ++i) { int idx = base + i; v[i] = (idx < n) ? hist[idx] : 0; s += v[i]; }
    tmp[tid] = s;
    __syncthreads();
    for (int off = 1; off < 256; off <<= 1) {
        int t = (tid >= off) ? tmp[tid - off] : 0;
        __syncthreads();
        tmp[tid] += t;
        __syncthreads();
    }
    int run = tmp[tid] - s;
    if (tid == 255) bsum[blockIdx.x] = tmp[255];
#pragma unroll
    for (int i = 0; i < 4; ++i) { int idx = base + i; if (idx < n) start[idx] = run; run += v[i]; }
}

__global__ __launch_bounds__(256) void scan2(int* __restrict__ bsum, int nb,
                                             int* __restrict__ start, int n) {
    __shared__ int tmp[256];
    const int tid = threadIdx.x;
    int v = (tid < nb) ? bsum[tid] : 0;
    tmp[tid] = v;
    __syncthreads();
    for (int off = 1; off < 256; off <<= 1) {
        int t = (tid >= off) ? tmp[tid - off] : 0;
        __syncthreads();
        tmp[tid] += t;
        __syncthreads();
    }
    if (tid < nb) bsum[tid] = tmp[tid] - v;
    if (tid == 255) start[n] = tmp[255];
}

__global__ __launch_bounds__(256) void scan3(int* __restrict__ start, int* __restrict__ cursor,
                                             const int* __restrict__ bsum, int n) {
    int off = bsum[blockIdx.x];
    int base = blockIdx.x * 1024 + threadIdx.x * 4;
#pragma unroll
    for (int i = 0; i < 4; ++i) {
        int j = base + i;
        if (j < n) { int v = start[j] + off; start[j] = v; cursor[j] = v; }
    }
}

// ---------------- CSR build: scatter source rows, sorted by col ----------------
__global__ void build_kernel(const int* __restrict__ row, const int* __restrict__ col,
                             int* __restrict__ cursor, int* __restrict__ srcrow, int E) {
    int e = blockIdx.x * blockDim.x + threadIdx.x;
    if (e >= E) return;
    int p = atomicAdd(&cursor[col[e]], 1);
    srcrow[p] = row[e];
}

// ---------------- graph boundaries from sorted batch: gstart[65] ----------------
__global__ void gbound_kernel(const int* __restrict__ batch, int* __restrict__ gstart, int n) {
    int i = blockIdx.x * blockDim.x + threadIdx.x;
    if (i >= n) return;
    int b = batch[i];
    int prev = (i == 0) ? -1 : batch[i - 1];
    for (int g = prev + 1; g <= b; ++g) gstart[g] = i;
    if (i == n - 1) {
        for (int g = b + 1; g <= NUM_GRAPHS; ++g) gstart[g] = n;
    }
}

// ---------------- GEMM via v_mfma_f64_16x16x4: C = A @ W (f64 accumulate) ----------------
__global__ __launch_bounds__(256, 4) void gemm128_mfma(const float* __restrict__ A,
                                                       const float* __restrict__ W,
                                                       float* __restrict__ C, int M, int act,
                                                       const double* __restrict__ scale) {
    __shared__ double As[32][33];
    __shared__ float  Ws[32][129];
    const int tid  = threadIdx.x;
    const int lane = tid & 63;
    const int wid  = tid >> 6;
    const int wrow = wid >> 1;
    const int wcol = wid & 1;
    const int rowBase = blockIdx.x * 32;

    d4 acc0 = {0.0, 0.0, 0.0, 0.0};
    d4 acc1 = {0.0, 0.0, 0.0, 0.0};
    d4 acc2 = {0.0, 0.0, 0.0, 0.0};
    d4 acc3 = {0.0, 0.0, 0.0, 0.0};

    const int lr = tid >> 3;
    const int lc = (tid & 7) * 4;
    const int wr = tid & 31;
    const int wc = (tid >> 5) * 16;

    const int growA = rowBase + lr;
    const bool haveA = (growA < M);

    float4 a0 = make_float4(0.f, 0.f, 0.f, 0.f);
    if (haveA) a0 = *reinterpret_cast<const float4*>(A + (size_t)growA * D + lc);

    const int arow = wrow * 16 + (lane & 15);
    const int asub = lane >> 4;
    const int bcol = wcol * 64 + (lane & 15);

    for (int kc = 0; kc < 128; kc += 32) {
        As[lr][lc + 0] = (double)a0.x;
        As[lr][lc + 1] = (double)a0.y;
        As[lr][lc + 2] = (double)a0.z;
        As[lr][lc + 3] = (double)a0.w;
        {
            const float4* src = reinterpret_cast<const float4*>(W + (size_t)(kc + wr) * D + wc);
#pragma unroll
            for (int i = 0; i < 4; ++i)
                *reinterpret_cast<float4*>(&Ws[wr][wc + 4 * i]) = src[i];
        }
        __syncthreads();

        if (kc + 32 < 128 && haveA)
            a0 = *reinterpret_cast<const float4*>(A + (size_t)growA * D + (kc + 32) + lc);

#pragma unroll
        for (int kk = 0; kk < 8; ++kk) {
            double av = As[arow][kk * 4 + asub];
            double b0 = (double)Ws[kk * 4 + asub][bcol +  0];
            double b1 = (double)Ws[kk * 4 + asub][bcol + 16];
            double b2 = (double)Ws[kk * 4 + asub][bcol + 32];
            double b3 = (double)Ws[kk * 4 + asub][bcol + 48];
            acc0 = __builtin_amdgcn_mfma_f64_16x16x4f64(av, b0, acc0, 0, 0, 0);
            acc1 = __builtin_amdgcn_mfma_f64_16x16x4f64(av, b1, acc1, 0, 0, 0);
            acc2 = __builtin_amdgcn_mfma_f64_16x16x4f64(av, b2, acc2, 0, 0, 0);
            acc3 = __builtin_amdgcn_mfma_f64_16x16x4f64(av, b3, acc3, 0, 0, 0);
        }
        __syncthreads();
    }

    const int rbase = rowBase + wrow * 16 + 4 * (lane >> 4);
    const int cb = wcol * 64 + (lane & 15);
#pragma unroll
    for (int r = 0; r < 4; ++r) {
        int grow = rbase + r;
        if (grow < M) {
            double sc = scale ? scale[grow] : 1.0;
            double v0 = acc0[r], v1 = acc1[r], v2 = acc2[r], v3 = acc3[r];
            if (act) { v0 = dleaky(v0); v1 = dleaky(v1); v2 = dleaky(v2); v3 = dleaky(v3); }
            v0 *= sc; v1 *= sc; v2 *= sc; v3 *= sc;
            float* crow = C + (size_t)grow * D + cb;
            crow[ 0] = (float)v0;
            crow[16] = (float)v1;
            crow[32] = (float)v2;
            crow[48] = (float)v3;
        }
    }
}

// ---------------- aggregation, feature-sliced for XCD L2 locality ----------------
// Work unit = (node, feature-half). fs = blockIdx.x & 1 so (with round-robin
// block->XCD striping) even XCDs only touch cols [0,64), odd XCDs [64,128):
// per-XCD unique h' bytes halve -> L3->L2 fetch ~halves. Correct under any
// placement. Each wave: 1 unit; lane = 1 feature (4B, 256B/wave coalesced).
// Per-output summation order identical to before (sequential CSR order).
__global__ __launch_bounds__(256) void agg_half(const float* __restrict__ hp,
                                                const int* __restrict__ srcrow,
                                                const int* __restrict__ start,
                                                const double* __restrict__ dinvd,
                                                float* __restrict__ out, int n) {
    const int bid  = blockIdx.x;
    const int fs   = bid & 1;
    const int node = (bid >> 1) * 4 + (int)(threadIdx.x >> 6);
    const int lane = threadIdx.x & 63;
    if (node >= n) return;
    int s = start[node], e = start[node + 1];
    double dn = dinvd[node];
    const int off = fs * 64 + lane;
    float hs = hp[(size_t)node * D + off];
    double ax = 0.0;
    int p = s;
    for (; p + 16 <= e; p += 16) {
        int r[16]; float hv[16];
#pragma unroll
        for (int i = 0; i < 16; ++i) r[i] = srcrow[p + i];
#pragma unroll
        for (int i = 0; i < 16; ++i) hv[i] = hp[(size_t)r[i] * D + off];
#pragma unroll
        for (int i = 0; i < 16; ++i) ax += (double)hv[i];
    }
    for (; p + 8 <= e; p += 8) {
        int r[8]; float hv[8];
#pragma unroll
        for (int i = 0; i < 8; ++i) r[i] = srcrow[p + i];
#pragma unroll
        for (int i = 0; i < 8; ++i) hv[i] = hp[(size_t)r[i] * D + off];
#pragma unroll
        for (int i = 0; i < 8; ++i) ax += (double)hv[i];
    }
    for (; p < e; ++p) {
        int r = srcrow[p];
        ax += (double)hp[(size_t)r * D + off];
    }
    ax = dleaky((ax + (double)hs) * dn);
    out[(size_t)node * D + off] = (float)ax;
}

// ---------------- fc2 (128->1): per-node scalar, f64 dot ----------------
__global__ __launch_bounds__(256) void fc2_d(const float* __restrict__ y,
                                             const float* __restrict__ w,
                                             double* __restrict__ s, int n) {
    int node = (int)((blockIdx.x * blockDim.x + threadIdx.x) >> 6);
    int lane = threadIdx.x & 63;
    if (node >= n) return;
    float2 yv = *reinterpret_cast<const float2*>(y + (size_t)node * D + lane * 2);
    float2 wv = *reinterpret_cast<const float2*>(w + lane * 2);
    double part = (double)yv.x * (double)wv.x + (double)yv.y * (double)wv.y;
#pragma unroll
    for (int off = 32; off > 0; off >>= 1) part += __shfl_down(part, off, 64);
    if (lane == 0) s[node] = dleaky(part);
}

// ---------------- pool: block per graph over its contiguous node range ----------------
__global__ __launch_bounds__(256) void pool2(const double* __restrict__ s,
                                             const int* __restrict__ gstart,
                                             float* __restrict__ out) {
    __shared__ double lsum[256];
    const int g = blockIdx.x;
    const int tid = threadIdx.x;
    const int s0 = gstart[g], s1 = gstart[g + 1];
    double sum = 0.0;
    for (int i = s0 + tid; i < s1; i += 256) sum += s[i];
    lsum[tid] = sum;
    __syncthreads();
    for (int off = 128; off > 0; off >>= 1) {
        if (tid < off) lsum[tid] += lsum[tid + off];
        __syncthreads();
    }
    if (tid == 0) {
        int cnt = s1 - s0;
        out[g] = (float)(lsum[0] / (double)(cnt > 0 ? cnt : 1));
    }
}

extern "C" void kernel_launch(void* const* d_in, const int* in_sizes, int n_in,
                              void* d_out, int out_size, void* d_ws, size_t ws_size,
                              hipStream_t stream) {
    const float* x    = (const float*)d_in[0];
    const int*   eidx = (const int*)d_in[1];
    const int*   batch= (const int*)d_in[2];
    const float* W0   = (const float*)d_in[3];
    const float* W1   = (const float*)d_in[4];
    const float* W2   = (const float*)d_in[5];
    const float* Wfc1 = (const float*)d_in[6];
    const float* Wfc2 = (const float*)d_in[7];
    float* out = (float*)d_out;

    const int* erow = eidx;
    const int* ecol = eidx + N_EDGES;

    char* ws = (char*)d_ws;
    int*    hist   = (int*)   (ws + 0);
    int*    start  = (int*)   (ws + 200064);
    int*    cursor = (int*)   (ws + 400384);   // dead after build -> reused as gstart
    int*    bsum   = (int*)   (ws + 600448);
    double* dinvd  = (double*)(ws + 600704);
    int*    srcrow = (int*)   (ws + 1000704);
    double* svec   = (double*)(ws + 4200704);
    float*  bufA   = (float*) (ws + 4600832);
    float*  bufB   = (float*) (ws + 30200832);
    int*    gstart = cursor;

    zero_kernel<<<(N_NODES + 255) / 256, 256, 0, stream>>>(hist, N_NODES);
    hist_kernel<<<(N_EDGES + 255) / 256, 256, 0, stream>>>(ecol, hist, N_EDGES);
    dinv_kernel<<<(N_NODES + 255) / 256, 256, 0, stream>>>(hist, dinvd, N_NODES);

    const int NB = (N_NODES + 1023) / 1024;  // 49
    scan1<<<NB, 256, 0, stream>>>(hist, start, bsum, N_NODES);
    scan2<<<1, 256, 0, stream>>>(bsum, NB, start, N_NODES);
    scan3<<<NB, 256, 0, stream>>>(start, cursor, bsum, N_NODES);

    build_kernel<<<(N_EDGES + 255) / 256, 256, 0, stream>>>(erow, ecol, cursor, srcrow, N_EDGES);
    gbound_kernel<<<(N_NODES + 255) / 256, 256, 0, stream>>>(batch, gstart, N_NODES);

    const int GEMM_GRID = (N_NODES + 31) / 32;       // 1563
    const int AGG_GRID  = 2 * ((N_NODES + 3) / 4);   // 25000 (node-quads x 2 halves)
    const int FC2_GRID  = (N_NODES + 3) / 4;

    gemm128_mfma<<<GEMM_GRID, 256, 0, stream>>>(x, W0, bufA, N_NODES, 0, dinvd);
    agg_half<<<AGG_GRID, 256, 0, stream>>>(bufA, srcrow, start, dinvd, bufB, N_NODES);
    gemm128_mfma<<<GEMM_GRID, 256, 0, stream>>>(bufB, W1, bufA, N_NODES, 0, dinvd);
    agg_half<<<AGG_GRID, 256, 0, stream>>>(bufA, srcrow, start, dinvd, bufB, N_NODES);
    gemm128_mfma<<<GEMM_GRID, 256, 0, stream>>>(bufB, W2, bufA, N_NODES, 0, dinvd);
    agg_half<<<AGG_GRID, 256, 0, stream>>>(bufA, srcrow, start, dinvd, bufB, N_NODES);
    gemm128_mfma<<<GEMM_GRID, 256, 0, stream>>>(bufB, Wfc1, bufA, N_NODES, 1, (const double*)nullptr);

    fc2_d<<<FC2_GRID, 256, 0, stream>>>(bufA, Wfc2, svec, N_NODES);
    pool2<<<NUM_GRAPHS, 256, 0, stream>>>(svec, gstart, out);
}